// Round 7
// baseline (145.815 us; speedup 1.0000x reference)
//
#include <hip/hip_runtime.h>

#define HH 192
#define WW 256
#define TH 8
#define TW 32
#define CCH 8            // channels per chunk
#define NCHUNK 8         // 64 / 8
#define THREADS 576      // 9 waves; wave w handles i = w - 4
#define CHSTEP (CCH * HH * WW)

typedef float f4 __attribute__((ext_vector_type(4)));

// async global->LDS, 16B per lane, dest = wave-uniform base + lane*16
#define GLL(gp, lp) __builtin_amdgcn_global_load_lds(                        \
    (const __attribute__((address_space(1))) unsigned int*)(gp),            \
    (__attribute__((address_space(3))) unsigned int*)(lp), 16, 0, 0)

// smem: x2 halo only, [2 buf][8 ch][16 rows][40 cols] floats = 10240 = 40 KiB.
// Linear (required by global_load_lds). Row stride 40 = 8 mod 32 gives the
// verified conflict-free b128 pattern (R6). x1 is NOT staged: all 9 waves
// want identical x1 addresses -> direct global loads, L1 broadcasts (R6 was
// LDS-bound; x1 was 25% of ds_reads and the 2-way-conflict bank pattern).
__global__ __launch_bounds__(THREADS) void cost_volume_kernel(
    const float* __restrict__ x1, const float* __restrict__ x2,
    float* __restrict__ out)
{
    __shared__ __align__(16) float smem[10240];

    const int tid  = threadIdx.x;
    const int wave = tid >> 6;      // 0..8 -> i = wave - 4
    const int lane = tid & 63;
    const int r    = lane >> 3;     // 0..7 tile row
    const int wcg  = lane & 7;      // 0..7 col group (4 px each)

    const int bid = blockIdx.x;
    const int b   = bid / 192;      // 24 h-tiles * 8 w-tiles
    const int rem = bid % 192;
    const int h0  = (rem >> 3) * TH;
    const int w0  = (rem & 7) * TW;

    // ---- x2 staging descriptors (16B units; chunk-invariant) ----
    // buffer = 1280 units: unit u -> ch=u/160, row=(u%160)/10, col4=u%10
    // LDS float offset = 4*u (layout is exactly linear in u).
    const int uA = tid;                       // 0..575   (all waves)
    const int uB = 576 + tid;                 // 576..1151 (all waves)
    const int uC = 1152 + tid;                // 1152..1279 (waves 0,1)
    const bool hC = (tid < 128);

    auto desc = [&](int u, bool& v, long& goff) {
        const int ch = u / 160, row = (u % 160) / 10, c4 = (u % 10) * 4;
        const int hg = h0 - 4 + row, wg = w0 - 4 + c4;
        v = (hg >= 0) & (hg < HH) & (wg >= 0) & (wg <= WW - 4);
        goff = ((long)(b * 64 + ch) * HH + hg) * WW + wg;
    };
    bool vA, vB, vC0; long gA, gB, gC;
    desc(uA, vA, gA);
    desc(uB, vB, gB);
    desc(uC, vC0, gC);
    const bool vC = vC0 & hC;

    auto issue = [&](int nb, int n) {
        const long cofs = (long)n * CHSTEP;
        float* const base = smem + nb * 5120;
        if (vA) GLL(x2 + gA + cofs, base + 256 * wave);
        if (vB) GLL(x2 + gB + cofs, base + 2304 + 256 * wave);
        if (vC) GLL(x2 + gC + cofs, base + 4608 + 256 * wave);
    };

    // ---- pre-zero LDS: OOB halo slots are never written by masked lanes ----
    const f4 z4 = {0.f, 0.f, 0.f, 0.f};
    for (int z = tid; z < 10240 / 4; z += THREADS) ((f4*)smem)[z] = z4;
    __syncthreads();

    issue(0, 0);
    __syncthreads();   // drains vmcnt(0) before s_barrier

    f4 acc0 = z4, acc1 = z4, acc2 = z4, acc3 = z4, acc4 = z4,
       acc5 = z4, acc6 = z4, acc7 = z4, acc8 = z4;

    const int row2 = r + 8 - wave;   // x2 halo row, in [0,15]
    // x1 direct-load base (ch 0), per-thread pixel group
    const float* x1p = x1 + ((long)(b * 64) * HH + (h0 + r)) * WW + w0 + wcg * 4;

    for (int n = 0; n < NCHUNK; ++n) {
        if (n + 1 < NCHUNK) issue((n + 1) & 1, n + 1);
        const float* sb2 = smem + (n & 1) * 5120 + row2 * 40 + wcg * 4;
        const float* x1c = x1p + (long)n * CHSTEP;

#define CV_CC(CC, AV)                                                        \
        {                                                                    \
            const f4 xv0 = *(const f4*)(sb2 + (CC) * 640);                   \
            const f4 xv1 = *(const f4*)(sb2 + (CC) * 640 + 4);               \
            const f4 xv2 = *(const f4*)(sb2 + (CC) * 640 + 8);               \
            const f4 w8 = xv0;                                               \
            const f4 w7 = __builtin_shufflevector(xv0, xv1, 1, 2, 3, 4);     \
            const f4 w6 = __builtin_shufflevector(xv0, xv1, 2, 3, 4, 5);     \
            const f4 w5 = __builtin_shufflevector(xv0, xv1, 3, 4, 5, 6);     \
            const f4 w4 = xv1;                                               \
            const f4 w3 = __builtin_shufflevector(xv1, xv2, 1, 2, 3, 4);     \
            const f4 w2 = __builtin_shufflevector(xv1, xv2, 2, 3, 4, 5);     \
            const f4 w1 = __builtin_shufflevector(xv1, xv2, 3, 4, 5, 6);     \
            const f4 w0 = xv2;                                               \
            acc0 = __builtin_elementwise_fma(AV, w0, acc0);                  \
            acc1 = __builtin_elementwise_fma(AV, w1, acc1);                  \
            acc2 = __builtin_elementwise_fma(AV, w2, acc2);                  \
            acc3 = __builtin_elementwise_fma(AV, w3, acc3);                  \
            acc4 = __builtin_elementwise_fma(AV, w4, acc4);                  \
            acc5 = __builtin_elementwise_fma(AV, w5, acc5);                  \
            acc6 = __builtin_elementwise_fma(AV, w6, acc6);                  \
            acc7 = __builtin_elementwise_fma(AV, w7, acc7);                  \
            acc8 = __builtin_elementwise_fma(AV, w8, acc8);                  \
        }

        // x1 loads in two batches of 4 (keeps live av regs <= 16)
        const f4 a0 = *(const f4*)(x1c);
        const f4 a1 = *(const f4*)(x1c + 1 * (HH * WW));
        const f4 a2 = *(const f4*)(x1c + 2 * (HH * WW));
        const f4 a3 = *(const f4*)(x1c + 3 * (HH * WW));
        CV_CC(0, a0)
        CV_CC(1, a1)
        const f4 a4 = *(const f4*)(x1c + 4 * (HH * WW));
        const f4 a5 = *(const f4*)(x1c + 5 * (HH * WW));
        const f4 a6 = *(const f4*)(x1c + 6 * (HH * WW));
        const f4 a7 = *(const f4*)(x1c + 7 * (HH * WW));
        CV_CC(2, a2)
        CV_CC(3, a3)
        CV_CC(4, a4)
        CV_CC(5, a5)
        CV_CC(6, a6)
        CV_CC(7, a7)
#undef CV_CC
        __syncthreads();
    }

    // ---- epilogue ----
    const float scale = 1.0f / 81.0f;
    const int hout = h0 + r;
    const int wout = w0 + wcg * 4;
    // k = (9*i + j) mod 81 = (9*wave + jj + 41) mod 81
#define CV_OUT(JJ)                                                           \
    {                                                                        \
        const int k = (9 * wave + (JJ) + 41) % 81;                           \
        float* po = out + (((long)b * 81 + k) * HH + hout) * WW + wout;      \
        *(f4*)po = acc##JJ * scale;                                          \
    }
    CV_OUT(0) CV_OUT(1) CV_OUT(2) CV_OUT(3) CV_OUT(4)
    CV_OUT(5) CV_OUT(6) CV_OUT(7) CV_OUT(8)
#undef CV_OUT
}

extern "C" void kernel_launch(void* const* d_in, const int* in_sizes, int n_in,
                              void* d_out, int out_size, void* d_ws, size_t ws_size,
                              hipStream_t stream) {
    const float* x1 = (const float*)d_in[0];
    const float* x2 = (const float*)d_in[1];
    float* out = (float*)d_out;
    dim3 grid(8 * 24 * 8);   // 1536 blocks
    dim3 block(THREADS);
    hipLaunchKernelGGL(cost_volume_kernel, grid, block, 0, stream, x1, x2, out);
}

// Round 8
// 115.763 us; speedup vs baseline: 1.2596x; 1.2596x over previous
//
#include <hip/hip_runtime.h>

#define HH 192
#define WW 256
#define TH 8
#define TW 32
#define CCH 4            // channels per chunk
#define NCHUNK 16        // 64 / 4
#define THREADS 576      // 9 waves; wave w handles i = w - 4
#define CHSTEP (CCH * HH * WW)

typedef float f4 __attribute__((ext_vector_type(4)));

// async global->LDS, 16B per lane, dest = wave-uniform base + lane*16
#define GLL(gp, lp) __builtin_amdgcn_global_load_lds(                        \
    (const __attribute__((address_space(1))) unsigned int*)(gp),            \
    (__attribute__((address_space(3))) unsigned int*)(lp), 16, 0, 0)

// smem layout (floats, linear in staged-unit order):
//   s1: [2 buf][4 ch][8 rows][32 cols]           = 2048 floats @ 0
//   s2: [2 buf][4 ch][16 rows][64 cols(40 data)] = 8192 floats @ 2048
// total 10240 floats = 40 KiB.
// R6/R7 evidence: ALL 21.2M conflict cycles came from x2 ds_reads at row
// stride 40 (≡8 mod 32 banks); x1's stride-32 (≡0) pattern had ZERO.
// So x2 rows get stride 64 (≡0 mod 32). global_load_lds needs a linear
// dest, so padding is done on the SOURCE side: pad units (col>=40) are
// masked off and never read; OOB halo slots stay pre-zeroed.
__global__ __launch_bounds__(THREADS) void cost_volume_kernel(
    const float* __restrict__ x1, const float* __restrict__ x2,
    float* __restrict__ out)
{
    __shared__ __align__(16) float smem[10240];

    const int tid  = threadIdx.x;
    const int wave = tid >> 6;      // 0..8 -> i = wave - 4
    const int lane = tid & 63;
    const int r    = lane >> 3;     // 0..7 tile row
    const int wcg  = lane & 7;      // 0..7 col group (4 px each)

    const int bid = blockIdx.x;
    const int b   = bid / 192;      // 24 h-tiles * 8 w-tiles
    const int rem = bid % 192;
    const int h0  = (rem >> 3) * TH;
    const int w0  = (rem & 7) * TW;

    // ---- x2 staging: [4 ch][16 rows][16 units/row] = 1024 units/chunk ----
    // unit u: ch=u>>8, row=(u>>4)&15, cu=u&15 (col=cu*4; cu<=9 is data).
    // 16 GLL instrs/chunk: instr i covers units [64i,64i+64). wave w does
    // i=w (all 9 waves) and i=w+9 (waves 0..6).
    auto desc2 = [&](int u, bool& v, long& goff) {
        const int ch = u >> 8, row = (u >> 4) & 15, cu = u & 15;
        const int hg = h0 - 4 + row, wg = w0 - 4 + cu * 4;
        v = (cu <= 9) & (hg >= 0) & (hg < HH) & (wg >= 0) & (wg <= WW - 4);
        goff = ((long)(b * 64 + ch) * HH + hg) * WW + wg;
    };
    bool vA, vB0; long gA, gB;
    desc2((wave << 6) + lane, vA, gA);
    desc2(((wave + 9) << 6) + lane, vB0, gB);
    const bool vB = vB0 & (wave <= 6);

    // ---- x1 staging: [4 ch][8 rows][8 units/row] = 256 units/chunk ----
    // waves 1..4, one GLL each: unit u1 = 64*(wave-1)+lane.
    const bool v1 = (wave >= 1) & (wave <= 4);
    const int w1 = (wave - 1) & 7;
    const int u1 = (w1 << 6) + lane;
    const int ch1 = u1 >> 6, r1 = (u1 >> 3) & 7, c1 = (u1 & 7) * 4;
    const long g1 = ((long)(b * 64 + ch1) * HH + (h0 + r1)) * WW + (w0 + c1);

    auto issue = [&](int nb, int n) {
        const long cofs = (long)n * CHSTEP;
        float* const b2 = smem + 2048 + nb * 4096;
        float* const b1 = smem + nb * 1024;
        if (vA) GLL(x2 + gA + cofs, b2 + (wave << 8));
        if (vB) GLL(x2 + gB + cofs, b2 + ((wave + 9) << 8));
        if (v1) GLL(x1 + g1 + cofs, b1 + (w1 << 8));
    };

    // ---- pre-zero LDS: OOB/pad slots are never written by masked lanes ----
    const f4 z4 = {0.f, 0.f, 0.f, 0.f};
    for (int z = tid; z < 10240 / 4; z += THREADS) ((f4*)smem)[z] = z4;
    __syncthreads();

    issue(0, 0);
    __syncthreads();   // drains vmcnt(0) before s_barrier

    f4 acc0 = z4, acc1 = z4, acc2 = z4, acc3 = z4, acc4 = z4,
       acc5 = z4, acc6 = z4, acc7 = z4, acc8 = z4;

    const int row2 = r + 8 - wave;   // x2 halo row, in [0,15]

    for (int n = 0; n < NCHUNK; ++n) {
        if (n + 1 < NCHUNK) issue((n + 1) & 1, n + 1);
        const float* sb1 = smem + (n & 1) * 1024 + r * 32 + wcg * 4;
        const float* sb2 = smem + 2048 + (n & 1) * 4096 + row2 * 64 + wcg * 4;
#pragma unroll
        for (int cc = 0; cc < CCH; ++cc) {
            const f4 av  = *(const f4*)(sb1 + cc * 256);
            const f4 xv0 = *(const f4*)(sb2 + cc * 1024);
            const f4 xv1 = *(const f4*)(sb2 + cc * 1024 + 4);
            const f4 xv2 = *(const f4*)(sb2 + cc * 1024 + 8);
            // out px p needs halo col wcg*4 + p + 8 - jj  (p=0..3)
            const f4 w8 = xv0;
            const f4 w7 = __builtin_shufflevector(xv0, xv1, 1, 2, 3, 4);
            const f4 w6 = __builtin_shufflevector(xv0, xv1, 2, 3, 4, 5);
            const f4 w5 = __builtin_shufflevector(xv0, xv1, 3, 4, 5, 6);
            const f4 w4 = xv1;
            const f4 w3 = __builtin_shufflevector(xv1, xv2, 1, 2, 3, 4);
            const f4 w2 = __builtin_shufflevector(xv1, xv2, 2, 3, 4, 5);
            const f4 w1w = __builtin_shufflevector(xv1, xv2, 3, 4, 5, 6);
            const f4 w0w = xv2;
            acc0 = __builtin_elementwise_fma(av, w0w, acc0);
            acc1 = __builtin_elementwise_fma(av, w1w, acc1);
            acc2 = __builtin_elementwise_fma(av, w2, acc2);
            acc3 = __builtin_elementwise_fma(av, w3, acc3);
            acc4 = __builtin_elementwise_fma(av, w4, acc4);
            acc5 = __builtin_elementwise_fma(av, w5, acc5);
            acc6 = __builtin_elementwise_fma(av, w6, acc6);
            acc7 = __builtin_elementwise_fma(av, w7, acc7);
            acc8 = __builtin_elementwise_fma(av, w8, acc8);
        }
        __syncthreads();
    }

    // ---- epilogue ----
    const float scale = 1.0f / 81.0f;
    const int hout = h0 + r;
    const int wout = w0 + wcg * 4;
    // k = (9*i + j) mod 81 = (9*wave + jj + 41) mod 81
#define CV_OUT(JJ)                                                           \
    {                                                                        \
        const int k = (9 * wave + (JJ) + 41) % 81;                           \
        float* po = out + (((long)b * 81 + k) * HH + hout) * WW + wout;      \
        *(f4*)po = acc##JJ * scale;                                          \
    }
    CV_OUT(0) CV_OUT(1) CV_OUT(2) CV_OUT(3) CV_OUT(4)
    CV_OUT(5) CV_OUT(6) CV_OUT(7) CV_OUT(8)
#undef CV_OUT
}

extern "C" void kernel_launch(void* const* d_in, const int* in_sizes, int n_in,
                              void* d_out, int out_size, void* d_ws, size_t ws_size,
                              hipStream_t stream) {
    const float* x1 = (const float*)d_in[0];
    const float* x2 = (const float*)d_in[1];
    float* out = (float*)d_out;
    dim3 grid(8 * 24 * 8);   // 1536 blocks
    dim3 block(THREADS);
    hipLaunchKernelGGL(cost_volume_kernel, grid, block, 0, stream, x1, x2, out);
}